// Round 1
// baseline (981.424 us; speedup 1.0000x reference)
//
#include <hip/hip_runtime.h>
#include <cstddef>

// Problem constants (fixed-shape problem)
#define DD   128      // feature dim
#define PP   8192     // nodes per level
#define KK   8        // in-edges per node
#define LLV  16       // levels
#define NN   131072   // total nodes
#define NE   65536    // edges per level (PP*KK)
#define NLVL 15       // levels with edges

__device__ __forceinline__ float4 ld4(const float* p) { return *(const float4*)p; }
__device__ __forceinline__ void st4(float* p, float4 v) { *(float4*)p = v; }

// 32-rows-per-(rg4 group) x 128-col GEMM from LDS: acc[4][4] = tbuf[rg4..rg4+3][:] @ wbuf
__device__ __forceinline__ void tile_gemm(const float* __restrict__ tbuf,
                                          const float* __restrict__ wbuf,
                                          int rg4, int c4, float acc[4][4]) {
#pragma unroll
  for (int i = 0; i < 4; i++)
#pragma unroll
    for (int j = 0; j < 4; j++) acc[i][j] = 0.f;
  const float4* wb4 = (const float4*)wbuf;
#pragma unroll 8
  for (int k = 0; k < 128; k++) {
    float4 wv = wb4[k * 32 + c4];
    float x0 = tbuf[(rg4 + 0) * 128 + k];
    float x1 = tbuf[(rg4 + 1) * 128 + k];
    float x2 = tbuf[(rg4 + 2) * 128 + k];
    float x3 = tbuf[(rg4 + 3) * 128 + k];
    acc[0][0] = fmaf(x0, wv.x, acc[0][0]);
    acc[0][1] = fmaf(x0, wv.y, acc[0][1]);
    acc[0][2] = fmaf(x0, wv.z, acc[0][2]);
    acc[0][3] = fmaf(x0, wv.w, acc[0][3]);
    acc[1][0] = fmaf(x1, wv.x, acc[1][0]);
    acc[1][1] = fmaf(x1, wv.y, acc[1][1]);
    acc[1][2] = fmaf(x1, wv.z, acc[1][2]);
    acc[1][3] = fmaf(x1, wv.w, acc[1][3]);
    acc[2][0] = fmaf(x2, wv.x, acc[2][0]);
    acc[2][1] = fmaf(x2, wv.y, acc[2][1]);
    acc[2][2] = fmaf(x2, wv.z, acc[2][2]);
    acc[2][3] = fmaf(x2, wv.w, acc[2][3]);
    acc[3][0] = fmaf(x3, wv.x, acc[3][0]);
    acc[3][1] = fmaf(x3, wv.y, acc[3][1]);
    acc[3][2] = fmaf(x3, wv.z, acc[3][2]);
    acc[3][3] = fmaf(x3, wv.w, acc[3][3]);
  }
}

// ---------------- Node transform: h = relu(x@w1+b1)@w2 + b2 ----------------
// 512 threads, 64-row tiles, grid = NN/64 = 2048
__global__ __launch_bounds__(512) void nt_kernel(
    const float* __restrict__ x,
    const float* __restrict__ w1, const float* __restrict__ b1,
    const float* __restrict__ w2, const float* __restrict__ b2,
    float* __restrict__ h) {
  __shared__ float wbuf[128 * 128];   // 64 KB
  __shared__ float tbuf[64 * 128];    // 32 KB
  int tid = threadIdx.x;
  int c4 = tid & 31;
  int rg4 = (tid >> 5) * 4;           // row group base 0..60
  size_t base = (size_t)blockIdx.x * 64;

  float4* wb4 = (float4*)wbuf;
#pragma unroll
  for (int j = 0; j < 8; j++) wb4[tid + j * 512] = ((const float4*)w1)[tid + j * 512];
#pragma unroll
  for (int j = 0; j < 4; j++)
    ((float4*)tbuf)[tid + j * 512] = ((const float4*)(x + base * 128))[tid + j * 512];
  __syncthreads();

  float acc[4][4];
  tile_gemm(tbuf, wbuf, rg4, c4, acc);
  float4 bv = ((const float4*)b1)[c4];
  float4 t[4];
#pragma unroll
  for (int i = 0; i < 4; i++) {
    t[i].x = fmaxf(acc[i][0] + bv.x, 0.f);
    t[i].y = fmaxf(acc[i][1] + bv.y, 0.f);
    t[i].z = fmaxf(acc[i][2] + bv.z, 0.f);
    t[i].w = fmaxf(acc[i][3] + bv.w, 0.f);
  }
  __syncthreads();
#pragma unroll
  for (int i = 0; i < 4; i++) ((float4*)tbuf)[(rg4 + i) * 32 + c4] = t[i];
#pragma unroll
  for (int j = 0; j < 8; j++) wb4[tid + j * 512] = ((const float4*)w2)[tid + j * 512];
  __syncthreads();

  tile_gemm(tbuf, wbuf, rg4, c4, acc);
  float4 b2v = ((const float4*)b2)[c4];
#pragma unroll
  for (int i = 0; i < 4; i++) {
    float4 o;
    o.x = acc[i][0] + b2v.x;
    o.y = acc[i][1] + b2v.y;
    o.z = acc[i][2] + b2v.z;
    o.w = acc[i][3] + b2v.w;
    st4(h + (base + rg4 + i) * 128 + c4 * 4, o);
  }
}

// ---------------- CSR build (reverse-edge transpose) ----------------
__global__ __launch_bounds__(256) void csr_count(const int* __restrict__ src_all,
                                                 int* __restrict__ deg) {
  int e = blockIdx.x * 256 + threadIdx.x;  // grid = 3840 -> exactly 15*65536
  int l = e >> 16;
  int q = src_all[e];
  atomicAdd(&deg[l * PP + q], 1);
}

__global__ __launch_bounds__(256) void csr_scan(const int* __restrict__ deg,
                                                int* __restrict__ offs,
                                                int* __restrict__ cursor) {
  int l = blockIdx.x;
  int t = threadIdx.x;
  const int* d = deg + l * PP;
  __shared__ int ssum[256];
  int loc[32];
  int s = 0;
#pragma unroll
  for (int j = 0; j < 32; j++) { loc[j] = d[t * 32 + j]; s += loc[j]; }
  ssum[t] = s;
  __syncthreads();
  // Hillis-Steele inclusive scan over 256
  for (int off = 1; off < 256; off <<= 1) {
    int v = (t >= off) ? ssum[t - off] : 0;
    __syncthreads();
    ssum[t] += v;
    __syncthreads();
  }
  int run = (t == 0) ? 0 : ssum[t - 1];
#pragma unroll
  for (int j = 0; j < 32; j++) {
    offs[l * (PP + 1) + t * 32 + j] = run;
    cursor[l * PP + t * 32 + j] = run;
    run += loc[j];
  }
  if (t == 255) offs[l * (PP + 1) + PP] = run;
}

__global__ __launch_bounds__(256) void csr_fill(const int* __restrict__ src_all,
                                                int* __restrict__ cursor,
                                                int* __restrict__ edges) {
  int e = blockIdx.x * 256 + threadIdx.x;
  int l = e >> 16;
  int q = src_all[e];
  int pos = atomicAdd(&cursor[l * PP + q], 1);
  edges[l * NE + pos] = (e & (NE - 1)) >> 3;   // dst node p of this fwd edge
}

// ---------------- Fused message-passing step ----------------
// grid = 512: blocks 0..255 = forward level `step`, 256..511 = reverse level 15-step
__global__ __launch_bounds__(256) void mp_step(
    const float* __restrict__ h,
    const int* __restrict__ src_all,
    const int* __restrict__ offs,
    const int* __restrict__ edges,
    const float* __restrict__ fw_upd_w, const float* __restrict__ fw_upd_b,
    const float* __restrict__ fw_pre_w, const float* __restrict__ fw_pre_b,
    const float* __restrict__ bw_upd_w, const float* __restrict__ bw_upd_b,
    const float* __restrict__ bw_pre_w, const float* __restrict__ bw_pre_b,
    const float* __restrict__ mf_in, float* __restrict__ mf_out,
    const float* __restrict__ mb_in, float* __restrict__ mb_out,
    float* __restrict__ out, int step) {
  __shared__ float wbuf[128 * 128];   // 64 KB
  __shared__ float tbuf[32 * 128];    // 16 KB
  int tid = threadIdx.x;
  int c4 = tid & 31;
  int rg4 = (tid >> 5) * 4;           // 0..28
  bool is_fwd = blockIdx.x < 256;
  int tile = (blockIdx.x & 255) * 32;
  int level = is_fwd ? step : 15 - step;
  const float* upd_w = is_fwd ? fw_upd_w : bw_upd_w;
  const float* upd_b = is_fwd ? fw_upd_b : bw_upd_b;
  const float* pre_w = is_fwd ? fw_pre_w : bw_pre_w;
  const float* pre_b = is_fwd ? fw_pre_b : bw_pre_b;
  const float* m_in  = is_fwd ? mf_in : mb_in;
  float* m_out       = is_fwd ? mf_out : mb_out;
  bool has_gather = (step > 0);
  bool has_mout   = (step < 15);
  int col_off = is_fwd ? 0 : 128;

  float4* wb4 = (float4*)wbuf;
#pragma unroll
  for (int j = 0; j < 16; j++) wb4[tid + j * 256] = ((const float4*)upd_w)[tid + j * 256];

  // ---- phase A: gather z into tbuf ----
  if (has_gather) {
    if (is_fwd) {
      const int* src = src_all + (step - 1) * NE;
#pragma unroll
      for (int i = 0; i < 4; i++) {
        int r = rg4 + i;
        int p = tile + r;
        float4 v[8];
#pragma unroll
        for (int k = 0; k < 8; k++) {
          int s = src[p * 8 + k];
          v[k] = ld4(m_in + (size_t)s * 128 + c4 * 4);
        }
        float4 a;
        a.x = ((v[0].x + v[1].x) + (v[2].x + v[3].x)) + ((v[4].x + v[5].x) + (v[6].x + v[7].x));
        a.y = ((v[0].y + v[1].y) + (v[2].y + v[3].y)) + ((v[4].y + v[5].y) + (v[6].y + v[7].y));
        a.z = ((v[0].z + v[1].z) + (v[2].z + v[3].z)) + ((v[4].z + v[5].z) + (v[6].z + v[7].z));
        a.w = ((v[0].w + v[1].w) + (v[2].w + v[3].w)) + ((v[4].w + v[5].w) + (v[6].w + v[7].w));
        a.x *= 0.125f; a.y *= 0.125f; a.z *= 0.125f; a.w *= 0.125f;
        ((float4*)tbuf)[r * 32 + c4] = a;
      }
    } else {
      const int* off_l = offs + level * (PP + 1);
      const int* ep = edges + level * NE;
#pragma unroll
      for (int i = 0; i < 4; i++) {
        int r = rg4 + i;
        int q = tile + r;
        int lo = off_l[q], hi = off_l[q + 1];
        float4 a = {0.f, 0.f, 0.f, 0.f};
        for (int idx = lo; idx < hi; idx++) {
          int p = ep[idx];
          float4 v = ld4(m_in + (size_t)p * 128 + c4 * 4);
          a.x += v.x; a.y += v.y; a.z += v.z; a.w += v.w;
        }
        float inv = (hi > lo) ? 1.0f / (float)(hi - lo) : 0.f;
        a.x *= inv; a.y *= inv; a.z *= inv; a.w *= inv;
        ((float4*)tbuf)[r * 32 + c4] = a;
      }
    }
  } else {
    float4 z = {0.f, 0.f, 0.f, 0.f};
#pragma unroll
    for (int i = 0; i < 4; i++) ((float4*)tbuf)[(rg4 + i) * 32 + c4] = z;
  }
  __syncthreads();

  // ---- phase B: u = relu(z@upd_w + upd_b) + h[level] ; write output half ----
  float acc[4][4];
  tile_gemm(tbuf, wbuf, rg4, c4, acc);
  float4 bv = ((const float4*)upd_b)[c4];
  float4 u[4];
#pragma unroll
  for (int i = 0; i < 4; i++) {
    int n = level * PP + tile + rg4 + i;
    float4 res = ld4(h + (size_t)n * 128 + c4 * 4);
    u[i].x = fmaxf(acc[i][0] + bv.x, 0.f) + res.x;
    u[i].y = fmaxf(acc[i][1] + bv.y, 0.f) + res.y;
    u[i].z = fmaxf(acc[i][2] + bv.z, 0.f) + res.z;
    u[i].w = fmaxf(acc[i][3] + bv.w, 0.f) + res.w;
    st4(out + (size_t)n * 256 + col_off + c4 * 4, u[i]);
  }
  __syncthreads();

  // ---- phase C: m_out = relu(u @ pre_w + pre_b) ----
  if (has_mout) {
#pragma unroll
    for (int i = 0; i < 4; i++) ((float4*)tbuf)[(rg4 + i) * 32 + c4] = u[i];
#pragma unroll
    for (int j = 0; j < 16; j++) wb4[tid + j * 256] = ((const float4*)pre_w)[tid + j * 256];
    __syncthreads();
    tile_gemm(tbuf, wbuf, rg4, c4, acc);
    float4 pv = ((const float4*)pre_b)[c4];
#pragma unroll
    for (int i = 0; i < 4; i++) {
      float4 m;
      m.x = fmaxf(acc[i][0] + pv.x, 0.f);
      m.y = fmaxf(acc[i][1] + pv.y, 0.f);
      m.z = fmaxf(acc[i][2] + pv.z, 0.f);
      m.w = fmaxf(acc[i][3] + pv.w, 0.f);
      st4(m_out + (size_t)(tile + rg4 + i) * 128 + c4 * 4, m);
    }
  }
}

extern "C" void kernel_launch(void* const* d_in, const int* in_sizes, int n_in,
                              void* d_out, int out_size, void* d_ws, size_t ws_size,
                              hipStream_t stream) {
  const float* x      = (const float*)d_in[0];
  const int*   src    = (const int*)d_in[1];
  const float* nt_w1  = (const float*)d_in[2];
  const float* nt_b1  = (const float*)d_in[3];
  const float* nt_w2  = (const float*)d_in[4];
  const float* nt_b2  = (const float*)d_in[5];
  const float* f_pre_w = (const float*)d_in[6];
  const float* f_pre_b = (const float*)d_in[7];
  const float* f_upd_w = (const float*)d_in[8];
  const float* f_upd_b = (const float*)d_in[9];
  const float* b_pre_w = (const float*)d_in[10];
  const float* b_pre_b = (const float*)d_in[11];
  const float* b_upd_w = (const float*)d_in[12];
  const float* b_upd_b = (const float*)d_in[13];
  float* out = (float*)d_out;

  float* wsf = (float*)d_ws;
  float* h   = wsf;                                  // NN*DD
  float* mf0 = h + (size_t)NN * DD;                  // PP*DD each
  float* mf1 = mf0 + (size_t)PP * DD;
  float* mb0 = mf1 + (size_t)PP * DD;
  float* mb1 = mb0 + (size_t)PP * DD;
  int* deg    = (int*)(mb1 + (size_t)PP * DD);       // NLVL*PP
  int* offs   = deg + NLVL * PP;                     // NLVL*(PP+1)
  int* cursor = offs + NLVL * (PP + 1);              // NLVL*PP
  int* edges  = cursor + NLVL * PP;                  // NLVL*NE

  hipMemsetAsync(deg, 0, (size_t)NLVL * PP * sizeof(int), stream);
  nt_kernel<<<NN / 64, 512, 0, stream>>>(x, nt_w1, nt_b1, nt_w2, nt_b2, h);
  csr_count<<<NLVL * NE / 256, 256, 0, stream>>>(src, deg);
  csr_scan<<<NLVL, 256, 0, stream>>>(deg, offs, cursor);
  csr_fill<<<NLVL * NE / 256, 256, 0, stream>>>(src, cursor, edges);

  for (int s = 0; s < 16; s++) {
    const float* mf_in = (s & 1) ? mf0 : mf1;
    float* mf_out      = (s & 1) ? mf1 : mf0;
    const float* mb_in = (s & 1) ? mb0 : mb1;
    float* mb_out      = (s & 1) ? mb1 : mb0;
    mp_step<<<512, 256, 0, stream>>>(h, src, offs, edges,
                                     f_upd_w, f_upd_b, f_pre_w, f_pre_b,
                                     b_upd_w, b_upd_b, b_pre_w, b_pre_b,
                                     mf_in, mf_out, mb_in, mb_out, out, s);
  }
}